// Round 14
// baseline (3686.397 us; speedup 1.0000x reference)
//
#include <hip/hip_runtime.h>
#include <cstddef>
#include <cstdint>

#define BB 64
#define TT 4096
#define HD 64
#define FP 72  // f16 feature stride: 144B = 9 x 16B granules -> uniform bank spread

typedef _Float16 f16;
typedef _Float16 f16x8 __attribute__((ext_vector_type(8)));
typedef _Float16 f16x4 __attribute__((ext_vector_type(4)));
typedef _Float16 f16x2 __attribute__((ext_vector_type(2)));
typedef float f32x4 __attribute__((ext_vector_type(4)));
typedef float v2f __attribute__((ext_vector_type(2)));

// lgkm-only barrier: no vmcnt(0) drain. Sound because global loads are
// consumed by the issuing thread and global stores are fire-and-forget.
__device__ __forceinline__ void bar_lgkm() {
    asm volatile("s_waitcnt lgkmcnt(0)\n\ts_barrier" ::: "memory");
}

// ---------------------------------------------------------------------------
// Stats pass 1: 256 blocks = (batch b = blk>>2, T-segment seg = blk&3).
// ---------------------------------------------------------------------------
__global__ __launch_bounds__(256) void stats_part(const float* __restrict__ x,
                                                  float* __restrict__ part) {
    const int b = blockIdx.x >> 2, seg = blockIdx.x & 3;
    const int f = threadIdx.x & 63, grp = threadIdx.x >> 6;
    const float* xb = x + (size_t)b * TT * HD + (size_t)seg * (TT / 4) * HD;
    float s = 0.f, s2 = 0.f;
    for (int t = grp; t < TT / 4; t += 4) {
        float v = xb[t * HD + f];
        s += v;
        s2 = fmaf(v, v, s2);
    }
    __shared__ float ls[4][64];
    __shared__ float ls2[4][64];
    ls[grp][f] = s;
    ls2[grp][f] = s2;
    __syncthreads();
    if (threadIdx.x < 64) {
        float ss = 0.f, ss2 = 0.f;
#pragma unroll
        for (int i = 0; i < 4; ++i) { ss += ls[i][f]; ss2 += ls2[i][f]; }
        part[blockIdx.x * HD + f] = ss;
        part[256 * HD + blockIdx.x * HD + f] = ss2;
    }
}

__global__ __launch_bounds__(64) void stats_fin(const float* __restrict__ part,
                                                float* __restrict__ stats) {
    const int b = blockIdx.x, f = threadIdx.x;
    float s = 0.f, s2 = 0.f;
#pragma unroll
    for (int seg = 0; seg < 4; ++seg) {
        s += part[(b * 4 + seg) * HD + f];
        s2 += part[256 * HD + (b * 4 + seg) * HD + f];
    }
    float mu = s * (1.0f / TT);
    float var = s2 * (1.0f / TT) - mu * mu;
    stats[b * HD + f] = mu;
    stats[BB * HD + b * HD + f] = rsqrtf(var + 1e-5f);
}

// ---------------------------------------------------------------------------
// MFMA recurrent kernel (round-8 structure; split MFMA chains; 1-rcp
// c-combine in ACT).
// 4 blocks x 16 batches, 512 threads (8 waves).
// Waves 0-3: layer1 gates(t); waves 4-7: layer0 gates(t+1). 1 barrier/step.
// ---------------------------------------------------------------------------
__global__ __launch_bounds__(512, 2) void rnn_mfma(
    const float* __restrict__ x,
    const float* __restrict__ Wih0, const float* __restrict__ Whh0,
    const float* __restrict__ bih0, const float* __restrict__ bhh0,
    const float* __restrict__ Wih1, const float* __restrict__ Whh1,
    const float* __restrict__ bih1, const float* __restrict__ bhh1,
    const float* __restrict__ stats,
    float* __restrict__ h1out) {
    const int blk = blockIdx.x;
    const int tid = threadIdx.x;
    const int lane = tid & 63;
    const int wid = tid >> 6;
    const bool L1w = (wid < 4);
    const int wq = wid & 3;
    const int ln15 = lane & 15;
    const int l16 = lane >> 4;

    __shared__ __align__(16) f16 hT0[2][16 * FP];     // h0 ping-pong [batch][feat]
    __shared__ __align__(16) f16 hT1[16][16 * FP];    // h1 ring (slot = t&15)
    __shared__ __align__(16) f16 xnb[2][8][16 * FP];  // xn chunk dbuf

    // ---- weight A-fragments -> AGPRs (verified round-6/8 block) ----
    const float* WA = L1w ? Wih1 : Whh0;   // multiplies h0(t)
    const float* WBm = L1w ? Whh1 : Wih0;  // multiplies h1(t-1) / xn(t+1)
    uint32_t aA[4][2][4], aB[4][2][4];
#pragma unroll
    for (int i = 0; i < 4; ++i) {
        const int row = 64 * i + 16 * wq + ln15;
#pragma unroll
        for (int kt = 0; kt < 2; ++kt) {
            const int fb = 32 * kt + 8 * l16;
            const float4 a0 = *(const float4*)&WA[row * HD + fb];
            const float4 a1 = *(const float4*)&WA[row * HD + fb + 4];
            const float4 b0 = *(const float4*)&WBm[row * HD + fb];
            const float4 b1 = *(const float4*)&WBm[row * HD + fb + 4];
            f16x8 ha = {(f16)a0.x, (f16)a0.y, (f16)a0.z, (f16)a0.w,
                        (f16)a1.x, (f16)a1.y, (f16)a1.z, (f16)a1.w};
            f16x8 hb = {(f16)b0.x, (f16)b0.y, (f16)b0.z, (f16)b0.w,
                        (f16)b1.x, (f16)b1.y, (f16)b1.z, (f16)b1.w};
            uint4 ua = __builtin_bit_cast(uint4, ha);
            uint4 ub = __builtin_bit_cast(uint4, hb);
            asm volatile("v_accvgpr_write_b32 %0, %1" : "=a"(aA[i][kt][0]) : "v"(ua.x));
            asm volatile("v_accvgpr_write_b32 %0, %1" : "=a"(aA[i][kt][1]) : "v"(ua.y));
            asm volatile("v_accvgpr_write_b32 %0, %1" : "=a"(aA[i][kt][2]) : "v"(ua.z));
            asm volatile("v_accvgpr_write_b32 %0, %1" : "=a"(aA[i][kt][3]) : "v"(ua.w));
            asm volatile("v_accvgpr_write_b32 %0, %1" : "=a"(aB[i][kt][0]) : "v"(ub.x));
            asm volatile("v_accvgpr_write_b32 %0, %1" : "=a"(aB[i][kt][1]) : "v"(ub.y));
            asm volatile("v_accvgpr_write_b32 %0, %1" : "=a"(aB[i][kt][2]) : "v"(ub.z));
            asm volatile("v_accvgpr_write_b32 %0, %1" : "=a"(aB[i][kt][3]) : "v"(ub.w));
        }
    }
    f16x8 wAf[4][2], wBf[4][2];
#pragma unroll
    for (int i = 0; i < 4; ++i)
#pragma unroll
        for (int kt = 0; kt < 2; ++kt) {
            uint4 ua = {aA[i][kt][0], aA[i][kt][1], aA[i][kt][2], aA[i][kt][3]};
            uint4 ub = {aB[i][kt][0], aB[i][kt][1], aB[i][kt][2], aB[i][kt][3]};
            wAf[i][kt] = __builtin_bit_cast(f16x8, ua);
            wBf[i][kt] = __builtin_bit_cast(f16x8, ub);
        }

    // bias folded into accumulator init
    const float* bi = L1w ? bih1 : bih0;
    const float* bh = L1w ? bhh1 : bhh0;
    f32x4 bias[4];
#pragma unroll
    for (int i = 0; i < 4; ++i)
#pragma unroll
        for (int r = 0; r < 4; ++r) {
            const int row = 64 * i + 16 * wq + 4 * l16 + r;
            bias[i][r] = bi[row] + bh[row];
        }

    // ---- staging constants: thread = (batch sb, feature pair f2) ----
    const int sb = tid >> 5;          // 0..15
    const int f2 = (tid & 31) * 2;    // 0,2,..,62
    const size_t gb = (size_t)blk * 16 + sb;
    const float mux = stats[gb * HD + f2];
    const float muy = stats[gb * HD + f2 + 1];
    const float rsx = stats[(size_t)BB * HD + gb * HD + f2];
    const float rsy = stats[(size_t)BB * HD + gb * HD + f2 + 1];
    const v2f aa = {rsx, rsy};
    const v2f bbv = {-mux * rsx, -muy * rsy};
    const float* xrow = x + gb * TT * HD;
    float* orow = h1out + gb * TT * HD;

    // zero hT0 (both) and hT1 ring
    for (int i = tid; i < 2 * 16 * FP / 2; i += 512) ((unsigned*)hT0)[i] = 0u;
    for (int i = tid; i < 16 * 16 * FP / 2; i += 512) ((unsigned*)hT1)[i] = 0u;

    // prologue: write chunk 0 directly; preload chunk 1 into xr[]
    v2f xr[8];
#pragma unroll
    for (int tau = 0; tau < 8; ++tau) {
        v2f v = *(const v2f*)&xrow[(size_t)tau * HD + f2];
        f16x2 xh;
        xh.x = (f16)fmaf(v.x, aa.x, bbv.x);
        xh.y = (f16)fmaf(v.y, aa.y, bbv.y);
        *(f16x2*)&xnb[0][tau][sb * FP + f2] = xh;
    }
#pragma unroll
    for (int tau = 0; tau < 8; ++tau)
        xr[tau] = *(const v2f*)&xrow[(size_t)(8 + tau) * HD + f2];

    v2f cstp[2] = {{0.f, 0.f}, {0.f, 0.f}};

    auto PHASE = [&](const f16* src1, const f16* src2, f16* dest) {
        f16x8 B1k0 = *(const f16x8*)&src1[ln15 * FP + 8 * l16];
        f16x8 B1k1 = *(const f16x8*)&src1[ln15 * FP + 32 + 8 * l16];
        f16x8 B2k0 = *(const f16x8*)&src2[ln15 * FP + 8 * l16];
        f16x8 B2k1 = *(const f16x8*)&src2[ln15 * FP + 32 + 8 * l16];
        f32x4 acc[4];
#pragma unroll
        for (int i = 0; i < 4; ++i) {
            // split into two independent 2-deep chains; merge with one add
            f32x4 accA = bias[i];
            f32x4 accB = (f32x4){0.f, 0.f, 0.f, 0.f};
            accA = __builtin_amdgcn_mfma_f32_16x16x32_f16(wAf[i][0], B1k0, accA, 0, 0, 0);
            accB = __builtin_amdgcn_mfma_f32_16x16x32_f16(wAf[i][1], B1k1, accB, 0, 0, 0);
            accA = __builtin_amdgcn_mfma_f32_16x16x32_f16(wBf[i][0], B2k0, accA, 0, 0, 0);
            accB = __builtin_amdgcn_mfma_f32_16x16x32_f16(wBf[i][1], B2k1, accB, 0, 0, 0);
            acc[i] = accA + accB;
        }
        // packed-f32 activations, cells paired (r=2rp, 2rp+1)
        // c = [c*(1+emi)(eg2+1) + (eg2-1)(1+emf)] / [(1+emf)(1+emi)(eg2+1)]
        uint32_t hw[2];
#pragma unroll
        for (int rp = 0; rp < 2; ++rp) {
            v2f gi = {acc[0][2 * rp], acc[0][2 * rp + 1]};
            v2f gf = {acc[1][2 * rp], acc[1][2 * rp + 1]};
            v2f gg = {acc[2][2 * rp], acc[2][2 * rp + 1]};
            v2f go = {acc[3][2 * rp], acc[3][2 * rp + 1]};
            v2f ti = gi * -1.44269504f;
            v2f tf = gf * -1.44269504f;
            v2f tg = gg * 2.88539008f;
            v2f to = go * -1.44269504f;
            v2f emi = {__builtin_amdgcn_exp2f(ti.x), __builtin_amdgcn_exp2f(ti.y)};
            v2f emf = {__builtin_amdgcn_exp2f(tf.x), __builtin_amdgcn_exp2f(tf.y)};
            v2f eg2 = {__builtin_amdgcn_exp2f(tg.x), __builtin_amdgcn_exp2f(tg.y)};
            v2f emo = {__builtin_amdgcn_exp2f(to.x), __builtin_amdgcn_exp2f(to.y)};
            v2f A = emi + 1.0f;       // 1+e^-i
            v2f F = emf + 1.0f;       // 1+e^-f
            v2f G2p = eg2 + 1.0f;
            v2f G2m = eg2 - 1.0f;
            v2f AG = A * G2p;
            v2f num = cstp[rp] * AG + G2m * F;
            v2f den = F * AG;
            v2f rc = {__builtin_amdgcn_rcpf(den.x), __builtin_amdgcn_rcpf(den.y)};
            v2f c = num * rc;
            cstp[rp] = c;
            v2f tc2 = c * 2.88539008f;
            v2f ec2 = {__builtin_amdgcn_exp2f(tc2.x), __builtin_amdgcn_exp2f(tc2.y)};
            v2f dno = (emo + 1.0f) * (ec2 + 1.0f);
            v2f rno = {__builtin_amdgcn_rcpf(dno.x), __builtin_amdgcn_rcpf(dno.y)};
            v2f h = (ec2 - 1.0f) * rno;
            f16x2 hh;
            hh.x = (f16)h.x;
            hh.y = (f16)h.y;
            hw[rp] = __builtin_bit_cast(uint32_t, hh);
        }
        uint2 hu = {hw[0], hw[1]};
        *(f16x4*)&dest[ln15 * FP + 16 * wq + 4 * l16] = __builtin_bit_cast(f16x4, hu);
    };

    bar_lgkm();
    if (!L1w) PHASE(&hT0[1][0], &xnb[0][0][0], &hT0[0][0]);  // layer-0 step 0
    bar_lgkm();

    for (int tb = 0; tb < TT; tb += 16) {
#pragma unroll
        for (int k = 0; k < 16; ++k) {
            // ---- compute phase (slot indices compile-time via k) ----
            {
                const f16* src1 = &hT0[k & 1][0];
                const f16* src2 = L1w ? &hT1[(k + 15) & 15][0]
                                      : &xnb[((k + 1) >> 3) & 1][(k + 1) & 7][0];
                f16* dest = L1w ? &hT1[k & 15][0] : &hT0[(k + 1) & 1][0];
                PHASE(src1, src2, dest);
            }
            // ---- even-spread staging ----
            // 1. flush h1 row (t-2)
            if (tb > 0 || k >= 2) {
                f16x2 hh = *(const f16x2*)&hT1[(k + 14) & 15][sb * FP + f2];
                v2f o = {(float)hh.x, (float)hh.y};
                *(v2f*)&orow[(size_t)(tb + k - 2) * HD + f2] = o;
            }
            {
                const int tc = k & 7;
                // 2. xnb write for time t+8 from xr[tc] (loaded 8 steps ago)
                if (k < 8 || tb < TT - 16) {
                    const int bufw = (k < 8) ? 1 : 0;
                    v2f v = xr[tc];
                    f16x2 xh;
                    xh.x = (f16)fmaf(v.x, aa.x, bbv.x);
                    xh.y = (f16)fmaf(v.y, aa.y, bbv.y);
                    *(f16x2*)&xnb[bufw][tc][sb * FP + f2] = xh;
                }
                // 3. issue load for time t+16
                if (tb < TT - 16) {
                    xr[tc] = *(const v2f*)&xrow[(size_t)(tb + 16 + k) * HD + f2];
                }
            }
            bar_lgkm();
        }
    }
    // epilogue: rows 4094, 4095
    {
        f16x2 h14 = *(const f16x2*)&hT1[14][sb * FP + f2];
        v2f o14 = {(float)h14.x, (float)h14.y};
        *(v2f*)&orow[(size_t)(TT - 2) * HD + f2] = o14;
        f16x2 h15 = *(const f16x2*)&hT1[15][sb * FP + f2];
        v2f o15 = {(float)h15.x, (float)h15.y};
        *(v2f*)&orow[(size_t)(TT - 1) * HD + f2] = o15;
    }
}

// ---------------------------------------------------------------------------
// FC + bias + residual, in place on d_out (hout holds h1, rewritten as out).
// ---------------------------------------------------------------------------
__global__ __launch_bounds__(256) void fc_res(float* __restrict__ hout,
                                              const float* __restrict__ x,
                                              const float* __restrict__ Wfc,
                                              const float* __restrict__ bfc) {
    __shared__ __align__(16) float wfc_lds[HD * HD];
    __shared__ float bfc_lds[HD];
    const int tid = threadIdx.x;
#pragma unroll
    for (int i = 0; i < 4; ++i)
        ((float4*)wfc_lds)[tid + 256 * i] = ((const float4*)Wfc)[tid + 256 * i];
    if (tid < HD) bfc_lds[tid] = bfc[tid];

    const size_t row = (size_t)blockIdx.x * 256 + tid;
    float hr[HD];
    {
        const float4* hp = (const float4*)(hout + row * HD);
#pragma unroll
        for (int i = 0; i < 16; ++i) {
            float4 v = hp[i];
            hr[4 * i] = v.x; hr[4 * i + 1] = v.y;
            hr[4 * i + 2] = v.z; hr[4 * i + 3] = v.w;
        }
    }
    __syncthreads();

    const float4* xp = (const float4*)(x + row * HD);
    float4* op = (float4*)(hout + row * HD);
    for (int j4 = 0; j4 < 16; ++j4) {
        float s0 = 0.f, s1 = 0.f, s2 = 0.f, s3 = 0.f;
        const float* w0 = &wfc_lds[(4 * j4 + 0) * HD];
        const float* w1 = &wfc_lds[(4 * j4 + 1) * HD];
        const float* w2 = &wfc_lds[(4 * j4 + 2) * HD];
        const float* w3 = &wfc_lds[(4 * j4 + 3) * HD];
#pragma unroll
        for (int k = 0; k < HD; ++k) {
            s0 = fmaf(w0[k], hr[k], s0);
            s1 = fmaf(w1[k], hr[k], s1);
            s2 = fmaf(w2[k], hr[k], s2);
            s3 = fmaf(w3[k], hr[k], s3);
        }
        float4 xv = xp[j4];
        float4 o;
        o.x = s0 + bfc_lds[4 * j4 + 0] + xv.x;
        o.y = s1 + bfc_lds[4 * j4 + 1] + xv.y;
        o.z = s2 + bfc_lds[4 * j4 + 2] + xv.z;
        o.w = s3 + bfc_lds[4 * j4 + 3] + xv.w;
        op[j4] = o;
    }
}

// ---------------------------------------------------------------------------
extern "C" void kernel_launch(void* const* d_in, const int* in_sizes, int n_in,
                              void* d_out, int out_size, void* d_ws, size_t ws_size,
                              hipStream_t stream) {
    const float* x    = (const float*)d_in[0];
    const float* Wih0 = (const float*)d_in[1];
    const float* Whh0 = (const float*)d_in[2];
    const float* bih0 = (const float*)d_in[3];
    const float* bhh0 = (const float*)d_in[4];
    const float* Wih1 = (const float*)d_in[5];
    const float* Whh1 = (const float*)d_in[6];
    const float* bih1 = (const float*)d_in[7];
    const float* bhh1 = (const float*)d_in[8];
    const float* Wfc  = (const float*)d_in[9];
    const float* bfc  = (const float*)d_in[10];

    float* part  = (float*)d_ws;                 // 2*256*64 floats = 128 KiB
    float* stats = part + 2 * 256 * HD;          // 2*64*64 floats  =  32 KiB
    float* out   = (float*)d_out;

    stats_part<<<256, 256, 0, stream>>>(x, part);
    stats_fin<<<64, 64, 0, stream>>>(part, stats);
    rnn_mfma<<<4, 512, 0, stream>>>(x, Wih0, Whh0, bih0, bhh0,
                                    Wih1, Whh1, bih1, bhh1, stats, out);
    fc_res<<<1024, 256, 0, stream>>>(out, x, Wfc, bfc);
}

// Round 15
// 3145.203 us; speedup vs baseline: 1.1721x; 1.1721x over previous
//
#include <hip/hip_runtime.h>
#include <cstddef>
#include <cstdint>

#define BB 64
#define TT 4096
#define HD 64
#define FP 72  // f16 feature stride: 144B = 9 x 16B granules -> uniform bank spread

typedef _Float16 f16;
typedef _Float16 f16x8 __attribute__((ext_vector_type(8)));
typedef _Float16 f16x4 __attribute__((ext_vector_type(4)));
typedef _Float16 f16x2 __attribute__((ext_vector_type(2)));
typedef float f32x4 __attribute__((ext_vector_type(4)));
typedef float v2f __attribute__((ext_vector_type(2)));

// lgkm-only barrier: no vmcnt(0) drain. Sound because global loads are
// consumed by the issuing thread and global stores are fire-and-forget.
__device__ __forceinline__ void bar_lgkm() {
    asm volatile("s_waitcnt lgkmcnt(0)\n\ts_barrier" ::: "memory");
}

// ---------------------------------------------------------------------------
// Stats pass 1: 256 blocks = (batch b = blk>>2, T-segment seg = blk&3).
// ---------------------------------------------------------------------------
__global__ __launch_bounds__(256) void stats_part(const float* __restrict__ x,
                                                  float* __restrict__ part) {
    const int b = blockIdx.x >> 2, seg = blockIdx.x & 3;
    const int f = threadIdx.x & 63, grp = threadIdx.x >> 6;
    const float* xb = x + (size_t)b * TT * HD + (size_t)seg * (TT / 4) * HD;
    float s = 0.f, s2 = 0.f;
    for (int t = grp; t < TT / 4; t += 4) {
        float v = xb[t * HD + f];
        s += v;
        s2 = fmaf(v, v, s2);
    }
    __shared__ float ls[4][64];
    __shared__ float ls2[4][64];
    ls[grp][f] = s;
    ls2[grp][f] = s2;
    __syncthreads();
    if (threadIdx.x < 64) {
        float ss = 0.f, ss2 = 0.f;
#pragma unroll
        for (int i = 0; i < 4; ++i) { ss += ls[i][f]; ss2 += ls2[i][f]; }
        part[blockIdx.x * HD + f] = ss;
        part[256 * HD + blockIdx.x * HD + f] = ss2;
    }
}

__global__ __launch_bounds__(64) void stats_fin(const float* __restrict__ part,
                                                float* __restrict__ stats) {
    const int b = blockIdx.x, f = threadIdx.x;
    float s = 0.f, s2 = 0.f;
#pragma unroll
    for (int seg = 0; seg < 4; ++seg) {
        s += part[(b * 4 + seg) * HD + f];
        s2 += part[256 * HD + (b * 4 + seg) * HD + f];
    }
    float mu = s * (1.0f / TT);
    float var = s2 * (1.0f / TT) - mu * mu;
    stats[b * HD + f] = mu;
    stats[BB * HD + b * HD + f] = rsqrtf(var + 1e-5f);
}

// ---------------------------------------------------------------------------
// MFMA recurrent kernel (round-8 structure exactly; exponent scales folded
// into weights so ACT uses exp2(acc) directly; 1-rcp c-combine).
// 4 blocks x 16 batches, 512 threads (8 waves).
// Waves 0-3: layer1 gates(t); waves 4-7: layer0 gates(t+1). 1 barrier/step.
// i,f,o rows scaled by -log2(e); g rows scaled by 2*log2(e) (and biases).
// ---------------------------------------------------------------------------
__global__ __launch_bounds__(512, 2) void rnn_mfma(
    const float* __restrict__ x,
    const float* __restrict__ Wih0, const float* __restrict__ Whh0,
    const float* __restrict__ bih0, const float* __restrict__ bhh0,
    const float* __restrict__ Wih1, const float* __restrict__ Whh1,
    const float* __restrict__ bih1, const float* __restrict__ bhh1,
    const float* __restrict__ stats,
    float* __restrict__ h1out) {
    const int blk = blockIdx.x;
    const int tid = threadIdx.x;
    const int lane = tid & 63;
    const int wid = tid >> 6;
    const bool L1w = (wid < 4);
    const int wq = wid & 3;
    const int ln15 = lane & 15;
    const int l16 = lane >> 4;

    __shared__ __align__(16) f16 hT0[2][16 * FP];     // h0 ping-pong [batch][feat]
    __shared__ __align__(16) f16 hT1[16][16 * FP];    // h1 ring (slot = t&15)
    __shared__ __align__(16) f16 xnb[2][8][16 * FP];  // xn chunk dbuf

    // ---- weight A-fragments -> AGPRs; exponent scales pre-folded ----
    const float* WA = L1w ? Wih1 : Whh0;   // multiplies h0(t)
    const float* WBm = L1w ? Whh1 : Wih0;  // multiplies h1(t-1) / xn(t+1)
    uint32_t aA[4][2][4], aB[4][2][4];
#pragma unroll
    for (int i = 0; i < 4; ++i) {
        const int row = 64 * i + 16 * wq + ln15;
        const float sc = (i == 2) ? 2.88539008f : -1.44269504f;
#pragma unroll
        for (int kt = 0; kt < 2; ++kt) {
            const int fb = 32 * kt + 8 * l16;
            const float4 a0 = *(const float4*)&WA[row * HD + fb];
            const float4 a1 = *(const float4*)&WA[row * HD + fb + 4];
            const float4 b0 = *(const float4*)&WBm[row * HD + fb];
            const float4 b1 = *(const float4*)&WBm[row * HD + fb + 4];
            f16x8 ha = {(f16)(a0.x * sc), (f16)(a0.y * sc), (f16)(a0.z * sc), (f16)(a0.w * sc),
                        (f16)(a1.x * sc), (f16)(a1.y * sc), (f16)(a1.z * sc), (f16)(a1.w * sc)};
            f16x8 hb = {(f16)(b0.x * sc), (f16)(b0.y * sc), (f16)(b0.z * sc), (f16)(b0.w * sc),
                        (f16)(b1.x * sc), (f16)(b1.y * sc), (f16)(b1.z * sc), (f16)(b1.w * sc)};
            uint4 ua = __builtin_bit_cast(uint4, ha);
            uint4 ub = __builtin_bit_cast(uint4, hb);
            asm volatile("v_accvgpr_write_b32 %0, %1" : "=a"(aA[i][kt][0]) : "v"(ua.x));
            asm volatile("v_accvgpr_write_b32 %0, %1" : "=a"(aA[i][kt][1]) : "v"(ua.y));
            asm volatile("v_accvgpr_write_b32 %0, %1" : "=a"(aA[i][kt][2]) : "v"(ua.z));
            asm volatile("v_accvgpr_write_b32 %0, %1" : "=a"(aA[i][kt][3]) : "v"(ua.w));
            asm volatile("v_accvgpr_write_b32 %0, %1" : "=a"(aB[i][kt][0]) : "v"(ub.x));
            asm volatile("v_accvgpr_write_b32 %0, %1" : "=a"(aB[i][kt][1]) : "v"(ub.y));
            asm volatile("v_accvgpr_write_b32 %0, %1" : "=a"(aB[i][kt][2]) : "v"(ub.z));
            asm volatile("v_accvgpr_write_b32 %0, %1" : "=a"(aB[i][kt][3]) : "v"(ub.w));
        }
    }
    f16x8 wAf[4][2], wBf[4][2];
#pragma unroll
    for (int i = 0; i < 4; ++i)
#pragma unroll
        for (int kt = 0; kt < 2; ++kt) {
            uint4 ua = {aA[i][kt][0], aA[i][kt][1], aA[i][kt][2], aA[i][kt][3]};
            uint4 ub = {aB[i][kt][0], aB[i][kt][1], aB[i][kt][2], aB[i][kt][3]};
            wAf[i][kt] = __builtin_bit_cast(f16x8, ua);
            wBf[i][kt] = __builtin_bit_cast(f16x8, ub);
        }

    // bias folded into accumulator init (same exponent scales)
    const float* bi = L1w ? bih1 : bih0;
    const float* bh = L1w ? bhh1 : bhh0;
    f32x4 bias[4];
#pragma unroll
    for (int i = 0; i < 4; ++i) {
        const float sc = (i == 2) ? 2.88539008f : -1.44269504f;
#pragma unroll
        for (int r = 0; r < 4; ++r) {
            const int row = 64 * i + 16 * wq + 4 * l16 + r;
            bias[i][r] = (bi[row] + bh[row]) * sc;
        }
    }

    // ---- staging constants: thread = (batch sb, feature pair f2) ----
    const int sb = tid >> 5;          // 0..15
    const int f2 = (tid & 31) * 2;    // 0,2,..,62
    const size_t gb = (size_t)blk * 16 + sb;
    const float mux = stats[gb * HD + f2];
    const float muy = stats[gb * HD + f2 + 1];
    const float rsx = stats[(size_t)BB * HD + gb * HD + f2];
    const float rsy = stats[(size_t)BB * HD + gb * HD + f2 + 1];
    const v2f aa = {rsx, rsy};
    const v2f bbv = {-mux * rsx, -muy * rsy};
    const float* xrow = x + gb * TT * HD;
    float* orow = h1out + gb * TT * HD;

    // zero hT0 (both) and hT1 ring
    for (int i = tid; i < 2 * 16 * FP / 2; i += 512) ((unsigned*)hT0)[i] = 0u;
    for (int i = tid; i < 16 * 16 * FP / 2; i += 512) ((unsigned*)hT1)[i] = 0u;

    // prologue: write chunk 0 directly; preload chunk 1 into xr[]
    v2f xr[8];
#pragma unroll
    for (int tau = 0; tau < 8; ++tau) {
        v2f v = *(const v2f*)&xrow[(size_t)tau * HD + f2];
        f16x2 xh;
        xh.x = (f16)fmaf(v.x, aa.x, bbv.x);
        xh.y = (f16)fmaf(v.y, aa.y, bbv.y);
        *(f16x2*)&xnb[0][tau][sb * FP + f2] = xh;
    }
#pragma unroll
    for (int tau = 0; tau < 8; ++tau)
        xr[tau] = *(const v2f*)&xrow[(size_t)(8 + tau) * HD + f2];

    v2f cstp[2] = {{0.f, 0.f}, {0.f, 0.f}};

    auto PHASE = [&](const f16* src1, const f16* src2, f16* dest) {
        f16x8 B1k0 = *(const f16x8*)&src1[ln15 * FP + 8 * l16];
        f16x8 B1k1 = *(const f16x8*)&src1[ln15 * FP + 32 + 8 * l16];
        f16x8 B2k0 = *(const f16x8*)&src2[ln15 * FP + 8 * l16];
        f16x8 B2k1 = *(const f16x8*)&src2[ln15 * FP + 32 + 8 * l16];
        f32x4 acc[4];
#pragma unroll
        for (int i = 0; i < 4; ++i) {
            acc[i] = bias[i];
            acc[i] = __builtin_amdgcn_mfma_f32_16x16x32_f16(wAf[i][0], B1k0, acc[i], 0, 0, 0);
            acc[i] = __builtin_amdgcn_mfma_f32_16x16x32_f16(wAf[i][1], B1k1, acc[i], 0, 0, 0);
            acc[i] = __builtin_amdgcn_mfma_f32_16x16x32_f16(wBf[i][0], B2k0, acc[i], 0, 0, 0);
            acc[i] = __builtin_amdgcn_mfma_f32_16x16x32_f16(wBf[i][1], B2k1, acc[i], 0, 0, 0);
        }
        // acc[0]=-1.4427*i, acc[1]=-1.4427*f, acc[2]=2.8854*g, acc[3]=-1.4427*o
        // emi=2^acc0=e^-i, emf=e^-f, eg2=e^{2g}, emo=e^-o
        // c = (c*A*G2p + G2m*F) / (F*A*G2p);  A=1+emi, F=1+emf, G2p=eg2+1
        uint32_t hw[2];
#pragma unroll
        for (int rp = 0; rp < 2; ++rp) {
            v2f gi = {acc[0][2 * rp], acc[0][2 * rp + 1]};
            v2f gf = {acc[1][2 * rp], acc[1][2 * rp + 1]};
            v2f gg = {acc[2][2 * rp], acc[2][2 * rp + 1]};
            v2f go = {acc[3][2 * rp], acc[3][2 * rp + 1]};
            v2f emi = {__builtin_amdgcn_exp2f(gi.x), __builtin_amdgcn_exp2f(gi.y)};
            v2f emf = {__builtin_amdgcn_exp2f(gf.x), __builtin_amdgcn_exp2f(gf.y)};
            v2f eg2 = {__builtin_amdgcn_exp2f(gg.x), __builtin_amdgcn_exp2f(gg.y)};
            v2f emo = {__builtin_amdgcn_exp2f(go.x), __builtin_amdgcn_exp2f(go.y)};
            v2f A = emi + 1.0f;
            v2f F = emf + 1.0f;
            v2f G2p = eg2 + 1.0f;
            v2f G2m = eg2 - 1.0f;
            v2f AG = A * G2p;
            v2f num = cstp[rp] * AG + G2m * F;
            v2f den = F * AG;
            v2f rc = {__builtin_amdgcn_rcpf(den.x), __builtin_amdgcn_rcpf(den.y)};
            v2f c = num * rc;
            cstp[rp] = c;
            v2f tc2 = c * 2.88539008f;
            v2f ec2 = {__builtin_amdgcn_exp2f(tc2.x), __builtin_amdgcn_exp2f(tc2.y)};
            v2f dno = (emo + 1.0f) * (ec2 + 1.0f);
            v2f rno = {__builtin_amdgcn_rcpf(dno.x), __builtin_amdgcn_rcpf(dno.y)};
            v2f h = (ec2 - 1.0f) * rno;
            f16x2 hh;
            hh.x = (f16)h.x;
            hh.y = (f16)h.y;
            hw[rp] = __builtin_bit_cast(uint32_t, hh);
        }
        uint2 hu = {hw[0], hw[1]};
        *(f16x4*)&dest[ln15 * FP + 16 * wq + 4 * l16] = __builtin_bit_cast(f16x4, hu);
    };

    bar_lgkm();
    if (!L1w) PHASE(&hT0[1][0], &xnb[0][0][0], &hT0[0][0]);  // layer-0 step 0
    bar_lgkm();

    for (int tb = 0; tb < TT; tb += 16) {
#pragma unroll
        for (int k = 0; k < 16; ++k) {
            // ---- compute phase (slot indices compile-time via k) ----
            {
                const f16* src1 = &hT0[k & 1][0];
                const f16* src2 = L1w ? &hT1[(k + 15) & 15][0]
                                      : &xnb[((k + 1) >> 3) & 1][(k + 1) & 7][0];
                f16* dest = L1w ? &hT1[k & 15][0] : &hT0[(k + 1) & 1][0];
                PHASE(src1, src2, dest);
            }
            // ---- even-spread staging ----
            // 1. flush h1 row (t-2)
            if (tb > 0 || k >= 2) {
                f16x2 hh = *(const f16x2*)&hT1[(k + 14) & 15][sb * FP + f2];
                v2f o = {(float)hh.x, (float)hh.y};
                *(v2f*)&orow[(size_t)(tb + k - 2) * HD + f2] = o;
            }
            {
                const int tc = k & 7;
                // 2. xnb write for time t+8 from xr[tc] (loaded 8 steps ago)
                if (k < 8 || tb < TT - 16) {
                    const int bufw = (k < 8) ? 1 : 0;
                    v2f v = xr[tc];
                    f16x2 xh;
                    xh.x = (f16)fmaf(v.x, aa.x, bbv.x);
                    xh.y = (f16)fmaf(v.y, aa.y, bbv.y);
                    *(f16x2*)&xnb[bufw][tc][sb * FP + f2] = xh;
                }
                // 3. issue load for time t+16
                if (tb < TT - 16) {
                    xr[tc] = *(const v2f*)&xrow[(size_t)(tb + 16 + k) * HD + f2];
                }
            }
            bar_lgkm();
        }
    }
    // epilogue: rows 4094, 4095
    {
        f16x2 h14 = *(const f16x2*)&hT1[14][sb * FP + f2];
        v2f o14 = {(float)h14.x, (float)h14.y};
        *(v2f*)&orow[(size_t)(TT - 2) * HD + f2] = o14;
        f16x2 h15 = *(const f16x2*)&hT1[15][sb * FP + f2];
        v2f o15 = {(float)h15.x, (float)h15.y};
        *(v2f*)&orow[(size_t)(TT - 1) * HD + f2] = o15;
    }
}

// ---------------------------------------------------------------------------
// FC + bias + residual, in place on d_out (hout holds h1, rewritten as out).
// ---------------------------------------------------------------------------
__global__ __launch_bounds__(256) void fc_res(float* __restrict__ hout,
                                              const float* __restrict__ x,
                                              const float* __restrict__ Wfc,
                                              const float* __restrict__ bfc) {
    __shared__ __align__(16) float wfc_lds[HD * HD];
    __shared__ float bfc_lds[HD];
    const int tid = threadIdx.x;
#pragma unroll
    for (int i = 0; i < 4; ++i)
        ((float4*)wfc_lds)[tid + 256 * i] = ((const float4*)Wfc)[tid + 256 * i];
    if (tid < HD) bfc_lds[tid] = bfc[tid];

    const size_t row = (size_t)blockIdx.x * 256 + tid;
    float hr[HD];
    {
        const float4* hp = (const float4*)(hout + row * HD);
#pragma unroll
        for (int i = 0; i < 16; ++i) {
            float4 v = hp[i];
            hr[4 * i] = v.x; hr[4 * i + 1] = v.y;
            hr[4 * i + 2] = v.z; hr[4 * i + 3] = v.w;
        }
    }
    __syncthreads();

    const float4* xp = (const float4*)(x + row * HD);
    float4* op = (float4*)(hout + row * HD);
    for (int j4 = 0; j4 < 16; ++j4) {
        float s0 = 0.f, s1 = 0.f, s2 = 0.f, s3 = 0.f;
        const float* w0 = &wfc_lds[(4 * j4 + 0) * HD];
        const float* w1 = &wfc_lds[(4 * j4 + 1) * HD];
        const float* w2 = &wfc_lds[(4 * j4 + 2) * HD];
        const float* w3 = &wfc_lds[(4 * j4 + 3) * HD];
#pragma unroll
        for (int k = 0; k < HD; ++k) {
            s0 = fmaf(w0[k], hr[k], s0);
            s1 = fmaf(w1[k], hr[k], s1);
            s2 = fmaf(w2[k], hr[k], s2);
            s3 = fmaf(w3[k], hr[k], s3);
        }
        float4 xv = xp[j4];
        float4 o;
        o.x = s0 + bfc_lds[4 * j4 + 0] + xv.x;
        o.y = s1 + bfc_lds[4 * j4 + 1] + xv.y;
        o.z = s2 + bfc_lds[4 * j4 + 2] + xv.z;
        o.w = s3 + bfc_lds[4 * j4 + 3] + xv.w;
        op[j4] = o;
    }
}

// ---------------------------------------------------------------------------
extern "C" void kernel_launch(void* const* d_in, const int* in_sizes, int n_in,
                              void* d_out, int out_size, void* d_ws, size_t ws_size,
                              hipStream_t stream) {
    const float* x    = (const float*)d_in[0];
    const float* Wih0 = (const float*)d_in[1];
    const float* Whh0 = (const float*)d_in[2];
    const float* bih0 = (const float*)d_in[3];
    const float* bhh0 = (const float*)d_in[4];
    const float* Wih1 = (const float*)d_in[5];
    const float* Whh1 = (const float*)d_in[6];
    const float* bih1 = (const float*)d_in[7];
    const float* bhh1 = (const float*)d_in[8];
    const float* Wfc  = (const float*)d_in[9];
    const float* bfc  = (const float*)d_in[10];

    float* part  = (float*)d_ws;                 // 2*256*64 floats = 128 KiB
    float* stats = part + 2 * 256 * HD;          // 2*64*64 floats  =  32 KiB
    float* out   = (float*)d_out;

    stats_part<<<256, 256, 0, stream>>>(x, part);
    stats_fin<<<64, 64, 0, stream>>>(part, stats);
    rnn_mfma<<<4, 512, 0, stream>>>(x, Wih0, Whh0, bih0, bhh0,
                                    Wih1, Whh1, bih1, bhh1, stats, out);
    fc_res<<<1024, 256, 0, stream>>>(out, x, Wfc, bfc);
}